// Round 1
// baseline (47.136 us; speedup 1.0000x reference)
//
#include <hip/hip_runtime.h>

#define DIM 384      // LN dim
#define RD  16       // reduced dim
#define PD  128      // pair_dim
#define MTILE 256    // m rows per block in main kernel
#define LN_EPS 1e-5f

// ---------------- Kernel A: LayerNorm + Linear(384->16) for x and y rows ----
// One 128-thread block per row. blockIdx.x in [0, M+N): first M rows are x,
// rest are y.
__global__ __launch_bounds__(128) void ln_reduce_kernel(
    const float* __restrict__ x, const float* __restrict__ y,
    const float* __restrict__ gamma, const float* __restrict__ beta,
    const float* __restrict__ w_red, const float* __restrict__ b_red,
    float* __restrict__ xr, float* __restrict__ yr, int M)
{
  int row = blockIdx.x;
  const float* src;
  float* dst;
  if (row < M) { src = x + (size_t)row * DIM;       dst = xr + (size_t)row * RD; }
  else         { src = y + (size_t)(row - M) * DIM; dst = yr + (size_t)(row - M) * RD; }

  int t = threadIdx.x;
  float v[3];
#pragma unroll
  for (int k = 0; k < 3; ++k) v[k] = src[t + k * 128];

  __shared__ float red[2];
  __shared__ float nrm[DIM];

  // mean
  float s = v[0] + v[1] + v[2];
#pragma unroll
  for (int off = 32; off; off >>= 1) s += __shfl_down(s, off);
  int wave = t >> 6, lane = t & 63;
  if (lane == 0) red[wave] = s;
  __syncthreads();
  float mu = (red[0] + red[1]) * (1.0f / DIM);
  __syncthreads();

  // variance (two-pass, matches reference numerics)
  float d0 = v[0] - mu, d1 = v[1] - mu, d2 = v[2] - mu;
  float s2 = d0 * d0 + d1 * d1 + d2 * d2;
#pragma unroll
  for (int off = 32; off; off >>= 1) s2 += __shfl_down(s2, off);
  if (lane == 0) red[wave] = s2;
  __syncthreads();
  float var = (red[0] + red[1]) * (1.0f / DIM);
  float rsig = rsqrtf(var + LN_EPS);

#pragma unroll
  for (int k = 0; k < 3; ++k) {
    int d = t + k * 128;
    nrm[d] = (v[k] - mu) * rsig * gamma[d] + beta[d];
  }
  __syncthreads();

  // project to 16: 8 threads per output column j, strided partials
  int j  = t >> 3;   // 0..15
  int k0 = t & 7;    // 0..7
  float p = 0.f;
  for (int e = k0; e < DIM; e += 8)
    p += nrm[e] * w_red[e * RD + j];
  p += __shfl_xor(p, 1);
  p += __shfl_xor(p, 2);
  p += __shfl_xor(p, 4);
  if (k0 == 0) dst[j] = p + b_red[j];
}

// ---------------- Kernel B: out[m,n,p] = b_out[p] + sum_i xr[m,i]*Wn[i,p] ---
// Wn[i,p] = sum_j yr[n,j] * w_out[i*16+j, p], built per-block in LDS.
// Grid: (M/MTILE, N). Block: 256 threads.
__global__ __launch_bounds__(256) void opm_kernel(
    const float* __restrict__ xr, const float* __restrict__ yr,
    const float* __restrict__ w_out, const float* __restrict__ b_out,
    float* __restrict__ out, int Nn)
{
  __shared__ float Wn[RD][PD];       // 8 KB
  __shared__ float xs[MTILE][RD];    // 16 KB
  __shared__ float yn[RD];

  int n  = blockIdx.y;
  int m0 = blockIdx.x * MTILE;
  int t  = threadIdx.x;

  if (t < RD) yn[t] = yr[n * RD + t];

  // stage xr tile: MTILE*RD = 4096 floats = 1024 float4, 4 per thread
  {
    float4* xsf = (float4*)&xs[0][0];
    const float4* xrf = (const float4*)(xr + (size_t)m0 * RD);
#pragma unroll
    for (int k = 0; k < 4; ++k) xsf[t + k * 256] = xrf[t + k * 256];
  }
  __syncthreads();  // yn ready

  // build Wn: thread handles p = t&127, i = (t>>7)*8 + k
  {
    int p  = t & 127;
    int i0 = (t >> 7) * 8;
#pragma unroll
    for (int k = 0; k < 8; ++k) {
      int i = i0 + k;
      float acc = 0.f;
#pragma unroll
      for (int j = 0; j < RD; ++j)
        acc += yn[j] * w_out[(size_t)(i * RD + j) * PD + p];
      Wn[i][p] = acc;
    }
  }
  __syncthreads();

  // main: 8 groups of 32 lanes; group g covers m = m0+g, step 8
  int p4 = (t & 31) * 4;
  int g  = t >> 5;

  float4 w[RD];
#pragma unroll
  for (int i = 0; i < RD; ++i) w[i] = *(const float4*)&Wn[i][p4];
  float4 bo = *(const float4*)&b_out[p4];

  for (int mi = g; mi < MTILE; mi += 8) {
    float xv[RD];
#pragma unroll
    for (int k = 0; k < 4; ++k)
      *(float4*)&xv[k * 4] = *(const float4*)&xs[mi][k * 4];

    float4 acc = bo;
#pragma unroll
    for (int i = 0; i < RD; ++i) {
      acc.x += xv[i] * w[i].x;
      acc.y += xv[i] * w[i].y;
      acc.z += xv[i] * w[i].z;
      acc.w += xv[i] * w[i].w;
    }
    size_t m = (size_t)(m0 + mi);
    *(float4*)&out[(m * Nn + n) * PD + p4] = acc;
  }
}

extern "C" void kernel_launch(void* const* d_in, const int* in_sizes, int n_in,
                              void* d_out, int out_size, void* d_ws, size_t ws_size,
                              hipStream_t stream) {
  const float* x        = (const float*)d_in[0];
  const float* y        = (const float*)d_in[1];
  const float* ln_gamma = (const float*)d_in[2];
  const float* ln_beta  = (const float*)d_in[3];
  const float* w_red    = (const float*)d_in[4];
  const float* b_red    = (const float*)d_in[5];
  const float* w_out    = (const float*)d_in[6];
  const float* b_out    = (const float*)d_in[7];
  float* out = (float*)d_out;

  int M = in_sizes[0] / DIM;   // 512
  int N = in_sizes[1] / DIM;   // 512

  float* xr = (float*)d_ws;            // M*16 floats
  float* yr = xr + (size_t)M * RD;     // N*16 floats

  ln_reduce_kernel<<<M + N, 128, 0, stream>>>(x, y, ln_gamma, ln_beta,
                                              w_red, b_red, xr, yr, M);

  dim3 grid(M / MTILE, N);
  opm_kernel<<<grid, 256, 0, stream>>>(xr, yr, w_out, b_out, out, N);
}

// Round 3
// 44.760 us; speedup vs baseline: 1.0531x; 1.0531x over previous
//
#include <hip/hip_runtime.h>

#define DIM 384      // LN dim
#define RD  16       // reduced dim
#define PD  128      // pair_dim
#define NN  512      // max n rows staged in LDS
#define LN_EPS 1e-5f

typedef float fx4 __attribute__((ext_vector_type(4)));

// ---------------- Kernel A: LayerNorm + Linear(384->16) for x and y rows ----
// One 128-thread block per row. blockIdx.x in [0, M+N): first M rows are x,
// rest are y.
__global__ __launch_bounds__(128) void ln_reduce_kernel(
    const float* __restrict__ x, const float* __restrict__ y,
    const float* __restrict__ gamma, const float* __restrict__ beta,
    const float* __restrict__ w_red, const float* __restrict__ b_red,
    float* __restrict__ xr, float* __restrict__ yr, int M)
{
  int row = blockIdx.x;
  const float* src;
  float* dst;
  if (row < M) { src = x + (size_t)row * DIM;       dst = xr + (size_t)row * RD; }
  else         { src = y + (size_t)(row - M) * DIM; dst = yr + (size_t)(row - M) * RD; }

  int t = threadIdx.x;
  float v[3];
#pragma unroll
  for (int k = 0; k < 3; ++k) v[k] = src[t + k * 128];

  __shared__ float red[2];
  __shared__ float nrm[DIM];

  // mean
  float s = v[0] + v[1] + v[2];
#pragma unroll
  for (int off = 32; off; off >>= 1) s += __shfl_down(s, off);
  int wave = t >> 6, lane = t & 63;
  if (lane == 0) red[wave] = s;
  __syncthreads();
  float mu = (red[0] + red[1]) * (1.0f / DIM);
  __syncthreads();

  // variance (two-pass, matches reference numerics)
  float d0 = v[0] - mu, d1 = v[1] - mu, d2 = v[2] - mu;
  float s2 = d0 * d0 + d1 * d1 + d2 * d2;
#pragma unroll
  for (int off = 32; off; off >>= 1) s2 += __shfl_down(s2, off);
  if (lane == 0) red[wave] = s2;
  __syncthreads();
  float var = (red[0] + red[1]) * (1.0f / DIM);
  float rsig = rsqrtf(var + LN_EPS);

#pragma unroll
  for (int k = 0; k < 3; ++k) {
    int d = t + k * 128;
    nrm[d] = (v[k] - mu) * rsig * gamma[d] + beta[d];
  }
  __syncthreads();

  // project to 16: 8 threads per output column j, strided partials
  int j  = t >> 3;   // 0..15
  int k0 = t & 7;    // 0..7
  float p = 0.f;
  for (int e = k0; e < DIM; e += 8)
    p += nrm[e] * w_red[e * RD + j];
  p += __shfl_xor(p, 1);
  p += __shfl_xor(p, 2);
  p += __shfl_xor(p, 4);
  if (k0 == 0) dst[j] = p + b_red[j];
}

// ---------------- Kernel B: one block per m, write contiguous out[m,:,:] ----
// Vm[j,p] = sum_i xr[m,i] * w_out[i*16+j, p]   (built once per block)
// out[m,n,p] = b_out[p] + sum_j yr[n,j] * Vm[j,p]
// Grid: M blocks of 512 threads. Block m writes 256 KB contiguous.
__global__ __launch_bounds__(512) void opm_kernel(
    const float* __restrict__ xr, const float* __restrict__ yr,
    const float* __restrict__ w_out, const float* __restrict__ b_out,
    float* __restrict__ out, int N)
{
  __shared__ float Vm[RD][PD];        // 8 KB
  __shared__ float yrs[NN * RD];      // 32 KB
  __shared__ float xm[RD];

  int m = blockIdx.x;
  int t = threadIdx.x;

  if (t < RD) xm[t] = xr[(size_t)m * RD + t];

  // stage yr: N*RD floats as fx4
  {
    fx4* d = (fx4*)yrs;
    const fx4* s4 = (const fx4*)yr;
    int total = N * RD / 4;
    for (int idx = t; idx < total; idx += 512) d[idx] = s4[idx];
  }
  __syncthreads();  // xm + yrs ready

  // build Vm: thread handles p = t&127, j = (t>>7)*4 + jj
  {
    int p  = t & 127;
    int j0 = (t >> 7) * 4;
#pragma unroll
    for (int jj = 0; jj < 4; ++jj) {
      int j = j0 + jj;
      float acc = 0.f;
#pragma unroll
      for (int i = 0; i < RD; ++i)
        acc += xm[i] * w_out[(size_t)(i * RD + j) * PD + p];
      Vm[j][p] = acc;
    }
  }
  __syncthreads();

  // main: 16 groups of 32 lanes; group g covers n = g, step 16
  int p4 = (t & 31) * 4;
  int g  = t >> 5;

  fx4 w[RD];
#pragma unroll
  for (int j = 0; j < RD; ++j) w[j] = *(const fx4*)&Vm[j][p4];
  fx4 bo = *(const fx4*)&b_out[p4];

  float* obase = out + (size_t)m * N * PD + p4;

#pragma unroll 2
  for (int n = g; n < N; n += 16) {
    float yv[RD];
#pragma unroll
    for (int k = 0; k < 4; ++k)
      *(fx4*)&yv[k * 4] = *(const fx4*)&yrs[n * RD + k * 4];

    fx4 acc = bo;
#pragma unroll
    for (int j = 0; j < RD; ++j)
      acc += yv[j] * w[j];
    __builtin_nontemporal_store(acc, (fx4*)(obase + (size_t)n * PD));
  }
}

extern "C" void kernel_launch(void* const* d_in, const int* in_sizes, int n_in,
                              void* d_out, int out_size, void* d_ws, size_t ws_size,
                              hipStream_t stream) {
  const float* x        = (const float*)d_in[0];
  const float* y        = (const float*)d_in[1];
  const float* ln_gamma = (const float*)d_in[2];
  const float* ln_beta  = (const float*)d_in[3];
  const float* w_red    = (const float*)d_in[4];
  const float* b_red    = (const float*)d_in[5];
  const float* w_out    = (const float*)d_in[6];
  const float* b_out    = (const float*)d_in[7];
  float* out = (float*)d_out;

  int M = in_sizes[0] / DIM;   // 512
  int N = in_sizes[1] / DIM;   // 512

  float* xr = (float*)d_ws;            // M*16 floats
  float* yr = xr + (size_t)M * RD;     // N*16 floats

  ln_reduce_kernel<<<M + N, 128, 0, stream>>>(x, y, ln_gamma, ln_beta,
                                              w_red, b_red, xr, yr, M);

  opm_kernel<<<M, 512, 0, stream>>>(xr, yr, w_out, b_out, out, N);
}